// Round 3
// baseline (54680.426 us; speedup 1.0000x reference)
//
#include <hip/hip_runtime.h>
#include <hip/hip_bf16.h>
#include <math.h>

// Problem constants
#define S   2048
#define E   256
#define HD  256
#define NCOL 2048   // 2 dirs * 4 gates * HD
#define NT  48

// ---------------- workspace layout (bytes) ----------------
#define XZ_OFF      ((size_t)0)                         // float[S][2048]
#define XZ_BYTES    ((size_t)S * 2048 * 4)
#define LSTM_OFF    (XZ_OFF + XZ_BYTES)                 // float[S][512]
#define LSTM_BYTES  ((size_t)S * 512 * 4)
#define FEATS_OFF   (LSTM_OFF + LSTM_BYTES)             // float[S][48]
#define FEATS_BYTES ((size_t)S * NT * 4)
#define BPS_OFF     (FEATS_OFF + FEATS_BYTES)           // u8[2048][48]
#define BPS_BYTES   ((size_t)S * NT)
#define PATHA_OFF   (BPS_OFF + BPS_BYTES)               // u8[3072][32]
#define PATHA_BYTES ((size_t)3072 * 32)

// =========================================================
// Kernel 1: xz[t][col] = emb[sent[t]] @ [Wih_f;Wih_b].T + [b_f;b_b]
// 128x128 tile, K=256 in chunks of 16, 256 threads, 8x8 per thread
// =========================================================
__global__ __launch_bounds__(256) void gemm_xz(
    const int* __restrict__ sent, const float* __restrict__ emb,
    const float* __restrict__ Wih_f, const float* __restrict__ Wih_b,
    const float* __restrict__ b_f, const float* __restrict__ b_b,
    float* __restrict__ xz)
{
    __shared__ float As[16][132];
    __shared__ float Bs[16][132];
    const int tid = threadIdx.x;
    const int bm = blockIdx.x * 128;   // t tile
    const int bn = blockIdx.y * 128;   // col tile
    const int tx = tid & 15, ty = tid >> 4;
    const int lm = tid >> 1, kq = (tid & 1) * 8;

    const int srow = sent[bm + lm];
    const float* arow = emb + (size_t)srow * E;
    const int bcol = bn + lm;
    const float* brow = (bcol < 1024) ? (Wih_f + (size_t)bcol * E)
                                      : (Wih_b + (size_t)(bcol - 1024) * E);
    float acc[8][8];
#pragma unroll
    for (int i = 0; i < 8; ++i)
#pragma unroll
        for (int j = 0; j < 8; ++j) acc[i][j] = 0.f;

    for (int k0 = 0; k0 < 256; k0 += 16) {
        float4 a0 = *(const float4*)(arow + k0 + kq);
        float4 a1 = *(const float4*)(arow + k0 + kq + 4);
        float4 c0v = *(const float4*)(brow + k0 + kq);
        float4 c1v = *(const float4*)(brow + k0 + kq + 4);
        __syncthreads();
        As[kq + 0][lm] = a0.x; As[kq + 1][lm] = a0.y; As[kq + 2][lm] = a0.z; As[kq + 3][lm] = a0.w;
        As[kq + 4][lm] = a1.x; As[kq + 5][lm] = a1.y; As[kq + 6][lm] = a1.z; As[kq + 7][lm] = a1.w;
        Bs[kq + 0][lm] = c0v.x; Bs[kq + 1][lm] = c0v.y; Bs[kq + 2][lm] = c0v.z; Bs[kq + 3][lm] = c0v.w;
        Bs[kq + 4][lm] = c1v.x; Bs[kq + 5][lm] = c1v.y; Bs[kq + 6][lm] = c1v.z; Bs[kq + 7][lm] = c1v.w;
        __syncthreads();
#pragma unroll
        for (int k = 0; k < 16; ++k) {
            float av[8], bv[8];
            *(float4*)&av[0] = *(const float4*)&As[k][ty * 8];
            *(float4*)&av[4] = *(const float4*)&As[k][ty * 8 + 4];
            *(float4*)&bv[0] = *(const float4*)&Bs[k][tx * 8];
            *(float4*)&bv[4] = *(const float4*)&Bs[k][tx * 8 + 4];
#pragma unroll
            for (int i = 0; i < 8; ++i)
#pragma unroll
                for (int j = 0; j < 8; ++j) acc[i][j] += av[i] * bv[j];
        }
    }
    // epilogue: add bias, store
    float bias[8];
    const int cb = bn + tx * 8;
    const float* bptr = (cb < 1024) ? (b_f + cb) : (b_b + cb - 1024);
    *(float4*)&bias[0] = *(const float4*)bptr;
    *(float4*)&bias[4] = *(const float4*)(bptr + 4);
#pragma unroll
    for (int i = 0; i < 8; ++i) {
        const int trow = bm + ty * 8 + i;
        float4 o0, o1;
        o0.x = acc[i][0] + bias[0]; o0.y = acc[i][1] + bias[1];
        o0.z = acc[i][2] + bias[2]; o0.w = acc[i][3] + bias[3];
        o1.x = acc[i][4] + bias[4]; o1.y = acc[i][5] + bias[5];
        o1.z = acc[i][6] + bias[6]; o1.w = acc[i][7] + bias[7];
        *(float4*)(xz + (size_t)trow * NCOL + cb) = o0;
        *(float4*)(xz + (size_t)trow * NCOL + cb + 4) = o1;
    }
}

// =========================================================
// DPP helpers: quad-lane butterfly add (no LDS pipe, pure VALU)
// =========================================================
template <int CTRL>
__device__ __forceinline__ float dpp_add(float x) {
    int xi = __float_as_int(x);
    int yi = __builtin_amdgcn_update_dpp(xi, xi, CTRL, 0xF, 0xF, true);
    return x + __int_as_float(yi);
}
#define DPP_XOR1 0xB1   // quad_perm:[1,0,3,2]
#define DPP_XOR2 0x4E   // quad_perm:[2,3,0,1]

// hbuf padding: +8 words per 64 -> the 4 k-slice bases land in
// different bank quads -> conflict-free broadcast reads
#define HPAD(i) ((i) + (((i) >> 6) << 3))

// =========================================================
// Kernel 2: LSTM recurrence, v3 — ONE WORKGROUP PER DIRECTION.
// 2 blocks x 1024 threads. All h exchange via LDS + __syncthreads.
// Thread (kg = tid&3, rgrp = tid>>2): owns rows rgrp*4..+3, k-slice
// [kg*64, kg*64+64). Weights: 256 fp32 in VGPRs. Per step:
//   read h16 (padded LDS, conflict-free) -> 256 FMA -> quad DPP
//   reduce -> zbuf -> barrier -> gates (tid<256) -> hbuf -> barrier.
// No cross-WG traffic at all.
// =========================================================
__global__ void __launch_bounds__(1024) lstm_rec(
    const float* __restrict__ Whh_f, const float* __restrict__ Whh_b,
    const float* __restrict__ h0, const float* __restrict__ c0,
    const float* __restrict__ xz, float* __restrict__ lstm_out)
{
    __shared__ float hbuf[288];      // 4 slices * 72 words
    __shared__ float zbuf[1024];
    const int dir = blockIdx.x;
    const int tid = threadIdx.x;
    const int kg = tid & 3;
    const int rgrp = tid >> 2;       // 0..255
    const float* Whh = dir ? Whh_b : Whh_f;

    // weights: 4 rows x 64 k in VGPRs
    float w[4][64];
#pragma unroll
    for (int m = 0; m < 4; ++m) {
        const float* wr = Whh + (size_t)(rgrp * 4 + m) * 256 + kg * 64;
#pragma unroll
        for (int k = 0; k < 64; k += 4) {
            float4 v = *(const float4*)(wr + k);
            w[m][k] = v.x; w[m][k + 1] = v.y; w[m][k + 2] = v.z; w[m][k + 3] = v.w;
        }
    }
    float cst = 0.f;
    if (tid < 256) {
        cst = c0[dir * 256 + tid];
        hbuf[HPAD(tid)] = h0[dir * 256 + tid];
    }
    __syncthreads();

    const int hbase = kg * 72;
    for (int step = 0; step < S; ++step) {
        const int tz = dir ? (S - 1 - step) : step;
        // prefetch xz for the gate phase (hidden under the FMA phase)
        float xzv0 = 0.f, xzv1 = 0.f, xzv2 = 0.f, xzv3 = 0.f;
        if (tid < 256) {
            const float* xp = xz + (size_t)tz * NCOL + dir * 1024 + tid;
            xzv0 = xp[0]; xzv1 = xp[256]; xzv2 = xp[512]; xzv3 = xp[768];
        }
        // matvec partials over this thread's k-slice
        float a0 = 0.f, a1 = 0.f, a2 = 0.f, a3 = 0.f;
#pragma unroll
        for (int k = 0; k < 64; k += 4) {
            float4 hv = *(const float4*)&hbuf[hbase + k];
            a0 += w[0][k] * hv.x; a0 += w[0][k + 1] * hv.y;
            a0 += w[0][k + 2] * hv.z; a0 += w[0][k + 3] * hv.w;
            a1 += w[1][k] * hv.x; a1 += w[1][k + 1] * hv.y;
            a1 += w[1][k + 2] * hv.z; a1 += w[1][k + 3] * hv.w;
            a2 += w[2][k] * hv.x; a2 += w[2][k + 1] * hv.y;
            a2 += w[2][k + 2] * hv.z; a2 += w[2][k + 3] * hv.w;
            a3 += w[3][k] * hv.x; a3 += w[3][k + 1] * hv.y;
            a3 += w[3][k + 2] * hv.z; a3 += w[3][k + 3] * hv.w;
        }
        // reduce across the 4 k-slices (quad lanes) via DPP
        a0 = dpp_add<DPP_XOR1>(a0); a0 = dpp_add<DPP_XOR2>(a0);
        a1 = dpp_add<DPP_XOR1>(a1); a1 = dpp_add<DPP_XOR2>(a1);
        a2 = dpp_add<DPP_XOR1>(a2); a2 = dpp_add<DPP_XOR2>(a2);
        a3 = dpp_add<DPP_XOR1>(a3); a3 = dpp_add<DPP_XOR2>(a3);
        if (kg == 0) {
            float4 o; o.x = a0; o.y = a1; o.z = a2; o.w = a3;
            *(float4*)&zbuf[rgrp * 4] = o;
        }
        __syncthreads();
        if (tid < 256) {
            const float zi = zbuf[tid]       + xzv0;
            const float zf = zbuf[256 + tid] + xzv1;
            const float zg = zbuf[512 + tid] + xzv2;
            const float zo = zbuf[768 + tid] + xzv3;
            const float ig = 1.f / (1.f + expf(-zi));
            const float fg = 1.f / (1.f + expf(-zf));
            const float gg = tanhf(zg);
            const float og = 1.f / (1.f + expf(-zo));
            cst = fg * cst + ig * gg;
            const float h = og * tanhf(cst);
            hbuf[HPAD(tid)] = h;
            lstm_out[(size_t)tz * 512 + dir * 256 + tid] = h;
        }
        __syncthreads();
    }
}

// =========================================================
// Kernel 3: feats[t][tag] = lstm_out[t] . W_out[tag] + b_out[tag]
// =========================================================
__global__ __launch_bounds__(256) void feats_k(
    const float* __restrict__ lstm, const float* __restrict__ Wout,
    const float* __restrict__ bout, float* __restrict__ feats)
{
    const int gid = blockIdx.x * 256 + threadIdx.x;
    if (gid >= S * NT) return;
    const int t = gid / NT, tag = gid - t * NT;
    const float* hr = lstm + (size_t)t * 512;
    const float* wr = Wout + (size_t)tag * 512;
    float s0 = 0, s1 = 0, s2 = 0, s3 = 0;
#pragma unroll 4
    for (int k = 0; k < 512; k += 4) {
        float4 h4 = *(const float4*)(hr + k);
        float4 w4 = *(const float4*)(wr + k);
        s0 += h4.x * w4.x; s1 += h4.y * w4.y;
        s2 += h4.z * w4.z; s3 += h4.w * w4.w;
    }
    feats[gid] = (s0 + s1) + (s2 + s3) + bout[tag];
}

// tournament combine: strict > keeps earlier index on ties (matches
// jnp.argmax first-occurrence), contiguous pairing preserves order
#define TCOMB(sa, ia, sb, ib, so, io) \
    { const bool g_ = (sb) > (sa); so = g_ ? (sb) : (sa); io = g_ ? (ib) : (ia); }

// =========================================================
// Kernel 4: Viterbi. Forward pass on a SINGLE WAVE (no __syncthreads
// in the 2048-step loop; wave-coherent LDS + lgkmcnt). Exact reference
// fp order: (v[i] + T[i,j]) + obs[j]; first-index tie-break via
// contiguous-pair tournament. Then chunked parallel backtrack (256 thr).
// =========================================================
__global__ void __launch_bounds__(256, 1) viterbi_k(
    const float* __restrict__ feats, const float* __restrict__ trans,
    unsigned char* __restrict__ bps, unsigned char* __restrict__ pathA,
    int* __restrict__ out)
{
    __shared__ float vbuf[NT];
    __shared__ unsigned char cmap[64][NT];
    __shared__ int SB[65];
    __shared__ int last_s;
    const int tid = threadIdx.x;

    if (tid < NT) vbuf[tid] = feats[tid];
    __syncthreads();

    if (tid < 64) {
        const int j = tid;
        const bool actj = (j < NT);
        const int jj = actj ? j : 0;
        float Tc[NT];
#pragma unroll
        for (int i = 0; i < NT; ++i) Tc[i] = trans[i * NT + jj];

        float obs_c = feats[NT + jj];
        for (int t = 1; t < S; ++t) {
            const float obs_n = (t < S - 1) ? feats[(size_t)(t + 1) * NT + jj] : 0.f;
            // read all v (wave-coherent LDS)
            float v[NT];
#pragma unroll
            for (int i = 0; i < NT; i += 4) {
                float4 q = *(const float4*)&vbuf[i];
                v[i] = q.x; v[i + 1] = q.y; v[i + 2] = q.z; v[i + 3] = q.w;
            }
            float sc[NT];
#pragma unroll
            for (int i = 0; i < NT; ++i) sc[i] = (v[i] + Tc[i]) + obs_c;
            // first-index argmax tournament: 48->24->12->6->3->1
            float s24[24]; int i24[24];
#pragma unroll
            for (int q = 0; q < 24; ++q)
                TCOMB(sc[2 * q], 2 * q, sc[2 * q + 1], 2 * q + 1, s24[q], i24[q]);
            float s12[12]; int i12[12];
#pragma unroll
            for (int q = 0; q < 12; ++q)
                TCOMB(s24[2 * q], i24[2 * q], s24[2 * q + 1], i24[2 * q + 1], s12[q], i12[q]);
            float s6[6]; int i6[6];
#pragma unroll
            for (int q = 0; q < 6; ++q)
                TCOMB(s12[2 * q], i12[2 * q], s12[2 * q + 1], i12[2 * q + 1], s6[q], i6[q]);
            float s3[3]; int i3[3];
#pragma unroll
            for (int q = 0; q < 3; ++q)
                TCOMB(s6[2 * q], i6[2 * q], s6[2 * q + 1], i6[2 * q + 1], s3[q], i3[q]);
            float sA; int iA;
            TCOMB(s3[0], i3[0], s3[1], i3[1], sA, iA);
            float sB; int iB;
            TCOMB(sA, iA, s3[2], i3[2], sB, iB);

            if (actj) {
                vbuf[j] = sB;
                bps[(size_t)(t - 1) * NT + j] = (unsigned char)iB;
            }
            asm volatile("s_waitcnt lgkmcnt(0)" ::: "memory");
            obs_c = obs_n;
        }
        // last = argmax of final v; first occurrence
        if (tid == 0) {
            float b = -1e30f; int bi = 0;
            for (int q = 0; q < NT; ++q) { if (vbuf[q] > b) { b = vbuf[q]; bi = q; } }
            last_s = bi;
        }
    }
    __syncthreads();

    // Phase A: 64 chunks x 48 states, 12 tasks/thread, ILP-12 chains
    int cArr[12], sArr[12];
    unsigned char stv[12];
#pragma unroll
    for (int r = 0; r < 12; ++r) {
        const int task = r * 256 + tid;
        cArr[r] = task / NT;
        sArr[r] = task - cArr[r] * NT;
        stv[r] = (unsigned char)sArr[r];
    }
    for (int stp = 31; stp >= 0; --stp) {
#pragma unroll
        for (int r = 0; r < 12; ++r) {
            const int km = cArr[r] * 32 + stp;
            if (km < S - 1) stv[r] = bps[(size_t)km * NT + stv[r]];
            pathA[(size_t)(cArr[r] * NT + sArr[r]) * 32 + stp] = stv[r];
        }
    }
#pragma unroll
    for (int r = 0; r < 12; ++r) cmap[cArr[r]][sArr[r]] = stv[r];
    __syncthreads();
    // Phase B: sequential chunk-boundary states
    if (tid == 0) {
        SB[64] = last_s;
        for (int c = 63; c >= 0; --c) SB[c] = cmap[c][SB[c + 1]];
    }
    __syncthreads();
    // Phase C: emit path
    for (int t = tid; t < S; t += 256) {
        const int c = t >> 5;
        out[t] = (int)pathA[(size_t)(c * NT + SB[c + 1]) * 32 + (t & 31)];
    }
}

// =========================================================
extern "C" void kernel_launch(void* const* d_in, const int* in_sizes, int n_in,
                              void* d_out, int out_size, void* d_ws, size_t ws_size,
                              hipStream_t stream) {
    const int*   sent   = (const int*)d_in[0];
    const float* emb    = (const float*)d_in[1];
    const float* Wih_f  = (const float*)d_in[2];
    const float* Whh_f  = (const float*)d_in[3];
    const float* b_f    = (const float*)d_in[4];
    const float* Wih_b  = (const float*)d_in[5];
    const float* Whh_b  = (const float*)d_in[6];
    const float* b_b    = (const float*)d_in[7];
    const float* W_out  = (const float*)d_in[8];
    const float* b_out  = (const float*)d_in[9];
    const float* trans  = (const float*)d_in[10];
    const float* h0     = (const float*)d_in[11];
    const float* c0     = (const float*)d_in[12];
    int* out = (int*)d_out;

    char* ws = (char*)d_ws;
    float* xz       = (float*)(ws + XZ_OFF);
    float* lstm     = (float*)(ws + LSTM_OFF);
    float* feats    = (float*)(ws + FEATS_OFF);
    unsigned char* bps   = (unsigned char*)(ws + BPS_OFF);
    unsigned char* pathA = (unsigned char*)(ws + PATHA_OFF);

    gemm_xz<<<dim3(16, 16), 256, 0, stream>>>(sent, emb, Wih_f, Wih_b, b_f, b_b, xz);

    lstm_rec<<<dim3(2), 1024, 0, stream>>>(Whh_f, Whh_b, h0, c0, xz, lstm);

    feats_k<<<dim3((S * NT + 255) / 256), 256, 0, stream>>>(lstm, W_out, b_out, feats);

    viterbi_k<<<dim3(1), 256, 0, stream>>>(feats, trans, bps, pathA, out);
}

// Round 5
// 15757.538 us; speedup vs baseline: 3.4701x; 3.4701x over previous
//
#include <hip/hip_runtime.h>
#include <hip/hip_bf16.h>
#include <math.h>

// Problem constants
#define S   2048
#define E   256
#define HD  256
#define NCOL 2048   // 2 dirs * 4 gates * HD
#define NT  48
#define NWG 16      // recurrence workgroups (8 per direction)

// ---------------- workspace layout (bytes) ----------------
#define XZ_OFF      ((size_t)0)                         // float[S][2048]
#define XZ_BYTES    ((size_t)S * 2048 * 4)
#define LSTM_OFF    (XZ_OFF + XZ_BYTES)                 // float[S][512]
#define LSTM_BYTES  ((size_t)S * 512 * 4)
#define FEATS_OFF   (LSTM_OFF + LSTM_BYTES)             // float[S][48]
#define FEATS_BYTES ((size_t)S * NT * 4)
#define HCUR_OFF    (FEATS_OFF + FEATS_BYTES)           // float[2 phase][2 dir][256]
#define HCUR_BYTES  ((size_t)2 * 2 * 256 * 4)
#define FLAG_OFF    (HCUR_OFF + HCUR_BYTES)             // unsigned[16][16] (64B-strided)
#define FLAG_BYTES  ((size_t)16 * 16 * 4)
#define BPS_OFF     (FLAG_OFF + FLAG_BYTES)             // u8[2048][48]
#define BPS_BYTES   ((size_t)S * NT)
#define PATHA_OFF   (BPS_OFF + BPS_BYTES)               // u8[3072][32]
#define PATHA_BYTES ((size_t)3072 * 32)

// =========================================================
// Device-scope bypass ops (work for ANY producer/consumer placement;
// no buffer_inv -> L2 stays warm for xz/weights).
// Loads: sc0 sc1 = bypass L1+L2, read coherence point.
// Stores: sc0 sc1 = write through to coherence point.
// Release = s_waitcnt vmcnt(0) then flag store (same wave as h stores).
// =========================================================
__device__ __forceinline__ unsigned ld_flag_dev(const unsigned* p) {
    unsigned v;
    asm volatile("global_load_dword %0, %1, off sc0 sc1\n\t"
                 "s_waitcnt vmcnt(0)"
                 : "=v"(v) : "v"(p) : "memory");
    return v;
}
__device__ __forceinline__ void ld_h16_dev(const float* p, float4& a, float4& b,
                                           float4& c, float4& d) {
    asm volatile(
        "global_load_dwordx4 %0, %4, off sc0 sc1\n\t"
        "global_load_dwordx4 %1, %4, off offset:16 sc0 sc1\n\t"
        "global_load_dwordx4 %2, %4, off offset:32 sc0 sc1\n\t"
        "global_load_dwordx4 %3, %4, off offset:48 sc0 sc1\n\t"
        "s_waitcnt vmcnt(0)"
        : "=&v"(a), "=&v"(b), "=&v"(c), "=&v"(d)
        : "v"(p)
        : "memory");
}
__device__ __forceinline__ void st_f32_dev(float* p, float v) {
    asm volatile("global_store_dword %0, %1, off sc0 sc1"
                 :: "v"(p), "v"(v) : "memory");
}
__device__ __forceinline__ void st_flag_rel_dev(unsigned* p, unsigned v) {
    asm volatile("s_waitcnt vmcnt(0)\n\t"
                 "global_store_dword %0, %1, off sc0 sc1"
                 :: "v"(p), "v"(v) : "memory");
}

// =========================================================
// Kernel 1: xz[t][col] = emb[sent[t]] @ [Wih_f;Wih_b].T + [b_f;b_b]
// =========================================================
__global__ __launch_bounds__(256) void gemm_xz(
    const int* __restrict__ sent, const float* __restrict__ emb,
    const float* __restrict__ Wih_f, const float* __restrict__ Wih_b,
    const float* __restrict__ b_f, const float* __restrict__ b_b,
    float* __restrict__ xz)
{
    __shared__ float As[16][132];
    __shared__ float Bs[16][132];
    const int tid = threadIdx.x;
    const int bm = blockIdx.x * 128;   // t tile
    const int bn = blockIdx.y * 128;   // col tile
    const int tx = tid & 15, ty = tid >> 4;
    const int lm = tid >> 1, kq = (tid & 1) * 8;

    const int srow = sent[bm + lm];
    const float* arow = emb + (size_t)srow * E;
    const int bcol = bn + lm;
    const float* brow = (bcol < 1024) ? (Wih_f + (size_t)bcol * E)
                                      : (Wih_b + (size_t)(bcol - 1024) * E);
    float acc[8][8];
#pragma unroll
    for (int i = 0; i < 8; ++i)
#pragma unroll
        for (int j = 0; j < 8; ++j) acc[i][j] = 0.f;

    for (int k0 = 0; k0 < 256; k0 += 16) {
        float4 a0 = *(const float4*)(arow + k0 + kq);
        float4 a1 = *(const float4*)(arow + k0 + kq + 4);
        float4 c0v = *(const float4*)(brow + k0 + kq);
        float4 c1v = *(const float4*)(brow + k0 + kq + 4);
        __syncthreads();
        As[kq + 0][lm] = a0.x; As[kq + 1][lm] = a0.y; As[kq + 2][lm] = a0.z; As[kq + 3][lm] = a0.w;
        As[kq + 4][lm] = a1.x; As[kq + 5][lm] = a1.y; As[kq + 6][lm] = a1.z; As[kq + 7][lm] = a1.w;
        Bs[kq + 0][lm] = c0v.x; Bs[kq + 1][lm] = c0v.y; Bs[kq + 2][lm] = c0v.z; Bs[kq + 3][lm] = c0v.w;
        Bs[kq + 4][lm] = c1v.x; Bs[kq + 5][lm] = c1v.y; Bs[kq + 6][lm] = c1v.z; Bs[kq + 7][lm] = c1v.w;
        __syncthreads();
#pragma unroll
        for (int k = 0; k < 16; ++k) {
            float av[8], bv[8];
            *(float4*)&av[0] = *(const float4*)&As[k][ty * 8];
            *(float4*)&av[4] = *(const float4*)&As[k][ty * 8 + 4];
            *(float4*)&bv[0] = *(const float4*)&Bs[k][tx * 8];
            *(float4*)&bv[4] = *(const float4*)&Bs[k][tx * 8 + 4];
#pragma unroll
            for (int i = 0; i < 8; ++i)
#pragma unroll
                for (int j = 0; j < 8; ++j) acc[i][j] += av[i] * bv[j];
        }
    }
    float bias[8];
    const int cb = bn + tx * 8;
    const float* bptr = (cb < 1024) ? (b_f + cb) : (b_b + cb - 1024);
    *(float4*)&bias[0] = *(const float4*)bptr;
    *(float4*)&bias[4] = *(const float4*)(bptr + 4);
#pragma unroll
    for (int i = 0; i < 8; ++i) {
        const int trow = bm + ty * 8 + i;
        float4 o0, o1;
        o0.x = acc[i][0] + bias[0]; o0.y = acc[i][1] + bias[1];
        o0.z = acc[i][2] + bias[2]; o0.w = acc[i][3] + bias[3];
        o1.x = acc[i][4] + bias[4]; o1.y = acc[i][5] + bias[5];
        o1.z = acc[i][6] + bias[6]; o1.w = acc[i][7] + bias[7];
        *(float4*)(xz + (size_t)trow * NCOL + cb) = o0;
        *(float4*)(xz + (size_t)trow * NCOL + cb + 4) = o1;
    }
}

// =========================================================
// Kernel 2: persistent bidirectional LSTM recurrence, v5.
// 16 WGs x 256 thr, fixed roles (wg>>3 = dir, wg&7 = wi) — no claiming,
// no placement assumptions. Sync via device-scope bypass ops only:
// producer stores h+flag with sc0 sc1 (through to coherence point),
// consumers poll + load h with sc0 sc1 (bypass L1+L2). No buffer_inv
// -> xz/weights stay cached. Weights pinned in VGPRs via asm touch.
// Compute structure identical to round-2 pass (bit-identical h).
// =========================================================
__global__ void __launch_bounds__(256, 2) lstm_rec(
    const float* __restrict__ Whh_f, const float* __restrict__ Whh_b,
    const float* __restrict__ h0, const float* __restrict__ c0,
    const float* __restrict__ xz, float* __restrict__ hcur,
    float* __restrict__ lstm_out, unsigned int* __restrict__ flags)
{
    __shared__ float red[4][16][8];
    __shared__ float actb[128];
    const int wg = blockIdx.x;
    const int dir = wg >> 3;        // 0 fwd, 1 bwd
    const int wi = wg & 7;          // index within direction
    const int ub = wi * 32;         // first hidden unit owned
    const int tid = threadIdx.x;
    const int kg = tid >> 4;        // 0..15  k-slice (16 wide)
    const int rg = tid & 15;        // 0..15  row group (8 rows each)
    const int k0 = kg * 16;
    const float* Whh = dir ? Whh_b : Whh_f;

    // load weights into registers: 8 rows x 16 k, pinned via asm touch
    float w[8][16];
#pragma unroll
    for (int q = 0; q < 8; ++q) {
        const int lr = rg * 8 + q;                      // 0..127
        const int grow = (lr >> 5) * 256 + ub + (lr & 31);
        const float* wr = Whh + (size_t)grow * 256 + k0;
#pragma unroll
        for (int kk = 0; kk < 16; kk += 4) {
            float4 v = *(const float4*)(wr + kk);
            w[q][kk] = v.x; w[q][kk + 1] = v.y; w[q][kk + 2] = v.z; w[q][kk + 3] = v.w;
        }
    }
#pragma unroll
    for (int q = 0; q < 8; ++q)
#pragma unroll
        for (int kk = 0; kk < 16; ++kk)
            asm volatile("" : "+v"(w[q][kk]));   // keep register-resident

    float cst = (tid < 32) ? c0[dir * 256 + ub + tid] : 0.f;
    // z-row mapping for tid<128: row = tid -> gate=tid>>5, unit=tid&31
    const int zcol = dir * 1024 + (tid >> 5) * 256 + ub + (tid & 31);
    // which producer's flag gates this thread's h16 slice [k0, k0+16)
    unsigned* myflag = flags + ((size_t)dir * 8 + (kg >> 1)) * 16;

    for (int step = 0; step < S; ++step) {
        // prefetch input part (plain cached load; independent of poll)
        float xzv = 0.f;
        if (tid < 128) {
            const int tz = dir ? (S - 1 - step) : step;
            xzv = xz[(size_t)tz * NCOL + zcol];
        }
        // wait for h(step-1) slice from the covering producer
        if (step > 0) {
            while (ld_flag_dev(myflag) < (unsigned)step) {}
        }
        const float* hsrc = (step == 0) ? (h0 + dir * 256 + k0)
                                        : (hcur + ((size_t)(step & 1) * 2 + dir) * 256 + k0);
        float4 hv0, hv1, hv2, hv3;
        ld_h16_dev(hsrc, hv0, hv1, hv2, hv3);
        float h16[16];
        h16[0]=hv0.x;  h16[1]=hv0.y;  h16[2]=hv0.z;  h16[3]=hv0.w;
        h16[4]=hv1.x;  h16[5]=hv1.y;  h16[6]=hv1.z;  h16[7]=hv1.w;
        h16[8]=hv2.x;  h16[9]=hv2.y;  h16[10]=hv2.z; h16[11]=hv2.w;
        h16[12]=hv3.x; h16[13]=hv3.y; h16[14]=hv3.z; h16[15]=hv3.w;

        float acc[8];
#pragma unroll
        for (int q = 0; q < 8; ++q) acc[q] = 0.f;
#pragma unroll
        for (int kk = 0; kk < 16; ++kk)
#pragma unroll
            for (int q = 0; q < 8; ++q) acc[q] += w[q][kk] * h16[kk];
        // butterfly over the 4 k-groups within this wave
#pragma unroll
        for (int q = 0; q < 8; ++q) {
            acc[q] += __shfl_xor(acc[q], 16);
            acc[q] += __shfl_xor(acc[q], 32);
        }
        if ((kg & 3) == 0) {
            const int wv = kg >> 2;
#pragma unroll
            for (int q = 0; q < 8; ++q) red[wv][rg][q] = acc[q];
        }
        __syncthreads();
        if (tid < 128) {
            const int rg2 = tid >> 3, q2 = tid & 7;
            const float z = ((red[0][rg2][q2] + red[1][rg2][q2]) +
                             (red[2][rg2][q2] + red[3][rg2][q2])) + xzv;
            const int gate = tid >> 5;
            actb[tid] = (gate == 2) ? tanhf(z) : (1.f / (1.f + expf(-z)));
        }
        __syncthreads();
        if (tid < 32) {
            const int u = tid;
            const float ig = actb[u];
            const float fg = actb[32 + u];
            const float gg = actb[64 + u];
            const float og = actb[96 + u];
            cst = fg * cst + ig * gg;
            const float h = og * tanhf(cst);
            const int tz = dir ? (S - 1 - step) : step;
            st_f32_dev(&hcur[(((size_t)((step + 1) & 1)) * 2 + dir) * 256 + ub + u], h);
            lstm_out[(size_t)tz * 512 + dir * 256 + ub + u] = h;   // plain (read next kernel)
        }
        // release: tid 0 is in the same wave as the h stores -> its
        // vmcnt(0) drains them before the flag becomes visible
        if (tid == 0) {
            st_flag_rel_dev(&flags[((size_t)dir * 8 + wi) * 16], (unsigned)(step + 1));
        }
    }
}

// =========================================================
// Kernel 3: feats[t][tag] = lstm_out[t] . W_out[tag] + b_out[tag]
// =========================================================
__global__ __launch_bounds__(256) void feats_k(
    const float* __restrict__ lstm, const float* __restrict__ Wout,
    const float* __restrict__ bout, float* __restrict__ feats)
{
    const int gid = blockIdx.x * 256 + threadIdx.x;
    if (gid >= S * NT) return;
    const int t = gid / NT, tag = gid - t * NT;
    const float* hr = lstm + (size_t)t * 512;
    const float* wr = Wout + (size_t)tag * 512;
    float s0 = 0, s1 = 0, s2 = 0, s3 = 0;
#pragma unroll 4
    for (int k = 0; k < 512; k += 4) {
        float4 h4 = *(const float4*)(hr + k);
        float4 w4 = *(const float4*)(wr + k);
        s0 += h4.x * w4.x; s1 += h4.y * w4.y;
        s2 += h4.z * w4.z; s3 += h4.w * w4.w;
    }
    feats[gid] = (s0 + s1) + (s2 + s3) + bout[tag];
}

// tournament combine: strict > keeps earlier index on ties (matches
// jnp.argmax first-occurrence), contiguous pairing preserves order
#define TCOMB(sa, ia, sb, ib, so, io) \
    { const bool g_ = (sb) > (sa); so = g_ ? (sb) : (sa); io = g_ ? (ib) : (ia); }

// =========================================================
// Kernel 4: Viterbi. Single-wave forward pass (no __syncthreads in the
// 2048-step loop), exact reference fp order, first-index tie-break.
// Then chunked parallel backtrack (256 thr).
// =========================================================
__global__ void __launch_bounds__(256, 1) viterbi_k(
    const float* __restrict__ feats, const float* __restrict__ trans,
    unsigned char* __restrict__ bps, unsigned char* __restrict__ pathA,
    int* __restrict__ out)
{
    __shared__ float vbuf[NT];
    __shared__ unsigned char cmap[64][NT];
    __shared__ int SB[65];
    __shared__ int last_s;
    const int tid = threadIdx.x;

    if (tid < NT) vbuf[tid] = feats[tid];
    __syncthreads();

    if (tid < 64) {
        const int j = tid;
        const bool actj = (j < NT);
        const int jj = actj ? j : 0;
        float Tc[NT];
#pragma unroll
        for (int i = 0; i < NT; ++i) Tc[i] = trans[i * NT + jj];

        float obs_c = feats[NT + jj];
        for (int t = 1; t < S; ++t) {
            const float obs_n = (t < S - 1) ? feats[(size_t)(t + 1) * NT + jj] : 0.f;
            float v[NT];
#pragma unroll
            for (int i = 0; i < NT; i += 4) {
                float4 q = *(const float4*)&vbuf[i];
                v[i] = q.x; v[i + 1] = q.y; v[i + 2] = q.z; v[i + 3] = q.w;
            }
            float sc[NT];
#pragma unroll
            for (int i = 0; i < NT; ++i) sc[i] = (v[i] + Tc[i]) + obs_c;
            float s24[24]; int i24[24];
#pragma unroll
            for (int q = 0; q < 24; ++q)
                TCOMB(sc[2 * q], 2 * q, sc[2 * q + 1], 2 * q + 1, s24[q], i24[q]);
            float s12[12]; int i12[12];
#pragma unroll
            for (int q = 0; q < 12; ++q)
                TCOMB(s24[2 * q], i24[2 * q], s24[2 * q + 1], i24[2 * q + 1], s12[q], i12[q]);
            float s6[6]; int i6[6];
#pragma unroll
            for (int q = 0; q < 6; ++q)
                TCOMB(s12[2 * q], i12[2 * q], s12[2 * q + 1], i12[2 * q + 1], s6[q], i6[q]);
            float s3[3]; int i3[3];
#pragma unroll
            for (int q = 0; q < 3; ++q)
                TCOMB(s6[2 * q], i6[2 * q], s6[2 * q + 1], i6[2 * q + 1], s3[q], i3[q]);
            float sA; int iA;
            TCOMB(s3[0], i3[0], s3[1], i3[1], sA, iA);
            float sB; int iB;
            TCOMB(sA, iA, s3[2], i3[2], sB, iB);

            if (actj) {
                vbuf[j] = sB;
                bps[(size_t)(t - 1) * NT + j] = (unsigned char)iB;
            }
            asm volatile("s_waitcnt lgkmcnt(0)" ::: "memory");
            obs_c = obs_n;
        }
        if (tid == 0) {
            float b = -1e30f; int bi = 0;
            for (int q = 0; q < NT; ++q) { if (vbuf[q] > b) { b = vbuf[q]; bi = q; } }
            last_s = bi;
        }
    }
    __syncthreads();

    // Phase A: 64 chunks x 48 states, 12 tasks/thread, ILP-12 chains
    int cArr[12], sArr[12];
    unsigned char stv[12];
#pragma unroll
    for (int r = 0; r < 12; ++r) {
        const int task = r * 256 + tid;
        cArr[r] = task / NT;
        sArr[r] = task - cArr[r] * NT;
        stv[r] = (unsigned char)sArr[r];
    }
    for (int stp = 31; stp >= 0; --stp) {
#pragma unroll
        for (int r = 0; r < 12; ++r) {
            const int km = cArr[r] * 32 + stp;
            if (km < S - 1) stv[r] = bps[(size_t)km * NT + stv[r]];
            pathA[(size_t)(cArr[r] * NT + sArr[r]) * 32 + stp] = stv[r];
        }
    }
#pragma unroll
    for (int r = 0; r < 12; ++r) cmap[cArr[r]][sArr[r]] = stv[r];
    __syncthreads();
    if (tid == 0) {
        SB[64] = last_s;
        for (int c = 63; c >= 0; --c) SB[c] = cmap[c][SB[c + 1]];
    }
    __syncthreads();
    for (int t = tid; t < S; t += 256) {
        const int c = t >> 5;
        out[t] = (int)pathA[(size_t)(c * NT + SB[c + 1]) * 32 + (t & 31)];
    }
}

// =========================================================
extern "C" void kernel_launch(void* const* d_in, const int* in_sizes, int n_in,
                              void* d_out, int out_size, void* d_ws, size_t ws_size,
                              hipStream_t stream) {
    const int*   sent   = (const int*)d_in[0];
    const float* emb    = (const float*)d_in[1];
    const float* Wih_f  = (const float*)d_in[2];
    const float* Whh_f  = (const float*)d_in[3];
    const float* b_f    = (const float*)d_in[4];
    const float* Wih_b  = (const float*)d_in[5];
    const float* Whh_b  = (const float*)d_in[6];
    const float* b_b    = (const float*)d_in[7];
    const float* W_out  = (const float*)d_in[8];
    const float* b_out  = (const float*)d_in[9];
    const float* trans  = (const float*)d_in[10];
    const float* h0     = (const float*)d_in[11];
    const float* c0     = (const float*)d_in[12];
    int* out = (int*)d_out;

    char* ws = (char*)d_ws;
    float* xz       = (float*)(ws + XZ_OFF);
    float* lstm     = (float*)(ws + LSTM_OFF);
    float* feats    = (float*)(ws + FEATS_OFF);
    float* hcur     = (float*)(ws + HCUR_OFF);
    unsigned* flags = (unsigned*)(ws + FLAG_OFF);
    unsigned char* bps   = (unsigned char*)(ws + BPS_OFF);
    unsigned char* pathA = (unsigned char*)(ws + PATHA_OFF);

    hipMemsetAsync(flags, 0, FLAG_BYTES, stream);

    gemm_xz<<<dim3(16, 16), 256, 0, stream>>>(sent, emb, Wih_f, Wih_b, b_f, b_b, xz);

    lstm_rec<<<dim3(NWG), 256, 0, stream>>>(Whh_f, Whh_b, h0, c0, xz,
                                            hcur, lstm, flags);

    feats_k<<<dim3((S * NT + 255) / 256), 256, 0, stream>>>(lstm, W_out, b_out, feats);

    viterbi_k<<<dim3(1), 256, 0, stream>>>(feats, trans, bps, pathA, out);
}

// Round 6
// 15662.880 us; speedup vs baseline: 3.4911x; 1.0060x over previous
//
#include <hip/hip_runtime.h>
#include <hip/hip_bf16.h>
#include <math.h>

// Problem constants
#define S   2048
#define E   256
#define HD  256
#define NCOL 2048   // 2 dirs * 4 gates * HD
#define NT  48
#define NWG 16      // recurrence workgroups (8 per direction)

// ---------------- workspace layout (bytes) ----------------
#define XZ_OFF      ((size_t)0)                         // float[S][2048]
#define XZ_BYTES    ((size_t)S * 2048 * 4)
#define LSTM_OFF    (XZ_OFF + XZ_BYTES)                 // float[S][512]
#define LSTM_BYTES  ((size_t)S * 512 * 4)
#define FEATS_OFF   (LSTM_OFF + LSTM_BYTES)             // float[S][48]
#define FEATS_BYTES ((size_t)S * NT * 4)
#define HCUR2_OFF   (FEATS_OFF + FEATS_BYTES)           // uint2[2 slot][2 dir][256]
#define HCUR2_BYTES ((size_t)2 * 2 * 256 * 8)
#define LAST_OFF    (HCUR2_OFF + HCUR2_BYTES)           // int[1] (padded 64B)
#define LAST_BYTES  ((size_t)64)
#define BPS_OFF     (LAST_OFF + LAST_BYTES)             // u8[2048][48]
#define BPS_BYTES   ((size_t)S * NT)
#define PATHA_OFF   (BPS_OFF + BPS_BYTES)               // u8[3072][32]
#define PATHA_BYTES ((size_t)3072 * 32)

// =========================================================
// Device-scope bypass ops. Data-as-flag: h stored as {f32 bits, step tag}
// uint2 per unit (single 8B store -> value+tag land atomically).
// Consumer polls the 16 pairs it needs (8 x dwordx4 sc0 sc1) and checks
// all 16 tags; success delivers the h data in the same loads.
// No separate flag, no producer-side vmcnt-before-flag leg.
// =========================================================
__device__ __forceinline__ void st_pair_dev(uint2* p, uint2 v) {
    asm volatile("global_store_dwordx2 %0, %1, off sc0 sc1"
                 :: "v"(p), "v"(v) : "memory");
}

__device__ __forceinline__ bool try_h16(const uint2* p, unsigned want,
                                        float h16[16]) {
    uint4 a, b, c, d, e, f, g, h;
    asm volatile(
        "global_load_dwordx4 %0, %8, off sc0 sc1\n\t"
        "global_load_dwordx4 %1, %8, off offset:16 sc0 sc1\n\t"
        "global_load_dwordx4 %2, %8, off offset:32 sc0 sc1\n\t"
        "global_load_dwordx4 %3, %8, off offset:48 sc0 sc1\n\t"
        "global_load_dwordx4 %4, %8, off offset:64 sc0 sc1\n\t"
        "global_load_dwordx4 %5, %8, off offset:80 sc0 sc1\n\t"
        "global_load_dwordx4 %6, %8, off offset:96 sc0 sc1\n\t"
        "global_load_dwordx4 %7, %8, off offset:112 sc0 sc1\n\t"
        "s_waitcnt vmcnt(0)"
        : "=&v"(a), "=&v"(b), "=&v"(c), "=&v"(d),
          "=&v"(e), "=&v"(f), "=&v"(g), "=&v"(h)
        : "v"(p)
        : "memory");
    const unsigned bad =
        (a.y ^ want) | (a.w ^ want) | (b.y ^ want) | (b.w ^ want) |
        (c.y ^ want) | (c.w ^ want) | (d.y ^ want) | (d.w ^ want) |
        (e.y ^ want) | (e.w ^ want) | (f.y ^ want) | (f.w ^ want) |
        (g.y ^ want) | (g.w ^ want) | (h.y ^ want) | (h.w ^ want);
    if (bad) return false;
    h16[0]  = __uint_as_float(a.x); h16[1]  = __uint_as_float(a.z);
    h16[2]  = __uint_as_float(b.x); h16[3]  = __uint_as_float(b.z);
    h16[4]  = __uint_as_float(c.x); h16[5]  = __uint_as_float(c.z);
    h16[6]  = __uint_as_float(d.x); h16[7]  = __uint_as_float(d.z);
    h16[8]  = __uint_as_float(e.x); h16[9]  = __uint_as_float(e.z);
    h16[10] = __uint_as_float(f.x); h16[11] = __uint_as_float(f.z);
    h16[12] = __uint_as_float(g.x); h16[13] = __uint_as_float(g.z);
    h16[14] = __uint_as_float(h.x); h16[15] = __uint_as_float(h.z);
    return true;
}

// =========================================================
// Kernel 1: xz[t][col] = emb[sent[t]] @ [Wih_f;Wih_b].T + [b_f;b_b]
// =========================================================
__global__ __launch_bounds__(256) void gemm_xz(
    const int* __restrict__ sent, const float* __restrict__ emb,
    const float* __restrict__ Wih_f, const float* __restrict__ Wih_b,
    const float* __restrict__ b_f, const float* __restrict__ b_b,
    float* __restrict__ xz)
{
    __shared__ float As[16][132];
    __shared__ float Bs[16][132];
    const int tid = threadIdx.x;
    const int bm = blockIdx.x * 128;   // t tile
    const int bn = blockIdx.y * 128;   // col tile
    const int tx = tid & 15, ty = tid >> 4;
    const int lm = tid >> 1, kq = (tid & 1) * 8;

    const int srow = sent[bm + lm];
    const float* arow = emb + (size_t)srow * E;
    const int bcol = bn + lm;
    const float* brow = (bcol < 1024) ? (Wih_f + (size_t)bcol * E)
                                      : (Wih_b + (size_t)(bcol - 1024) * E);
    float acc[8][8];
#pragma unroll
    for (int i = 0; i < 8; ++i)
#pragma unroll
        for (int j = 0; j < 8; ++j) acc[i][j] = 0.f;

    for (int k0 = 0; k0 < 256; k0 += 16) {
        float4 a0 = *(const float4*)(arow + k0 + kq);
        float4 a1 = *(const float4*)(arow + k0 + kq + 4);
        float4 c0v = *(const float4*)(brow + k0 + kq);
        float4 c1v = *(const float4*)(brow + k0 + kq + 4);
        __syncthreads();
        As[kq + 0][lm] = a0.x; As[kq + 1][lm] = a0.y; As[kq + 2][lm] = a0.z; As[kq + 3][lm] = a0.w;
        As[kq + 4][lm] = a1.x; As[kq + 5][lm] = a1.y; As[kq + 6][lm] = a1.z; As[kq + 7][lm] = a1.w;
        Bs[kq + 0][lm] = c0v.x; Bs[kq + 1][lm] = c0v.y; Bs[kq + 2][lm] = c0v.z; Bs[kq + 3][lm] = c0v.w;
        Bs[kq + 4][lm] = c1v.x; Bs[kq + 5][lm] = c1v.y; Bs[kq + 6][lm] = c1v.z; Bs[kq + 7][lm] = c1v.w;
        __syncthreads();
#pragma unroll
        for (int k = 0; k < 16; ++k) {
            float av[8], bv[8];
            *(float4*)&av[0] = *(const float4*)&As[k][ty * 8];
            *(float4*)&av[4] = *(const float4*)&As[k][ty * 8 + 4];
            *(float4*)&bv[0] = *(const float4*)&Bs[k][tx * 8];
            *(float4*)&bv[4] = *(const float4*)&Bs[k][tx * 8 + 4];
#pragma unroll
            for (int i = 0; i < 8; ++i)
#pragma unroll
                for (int j = 0; j < 8; ++j) acc[i][j] += av[i] * bv[j];
        }
    }
    float bias[8];
    const int cb = bn + tx * 8;
    const float* bptr = (cb < 1024) ? (b_f + cb) : (b_b + cb - 1024);
    *(float4*)&bias[0] = *(const float4*)bptr;
    *(float4*)&bias[4] = *(const float4*)(bptr + 4);
#pragma unroll
    for (int i = 0; i < 8; ++i) {
        const int trow = bm + ty * 8 + i;
        float4 o0, o1;
        o0.x = acc[i][0] + bias[0]; o0.y = acc[i][1] + bias[1];
        o0.z = acc[i][2] + bias[2]; o0.w = acc[i][3] + bias[3];
        o1.x = acc[i][4] + bias[4]; o1.y = acc[i][5] + bias[5];
        o1.z = acc[i][6] + bias[6]; o1.w = acc[i][7] + bias[7];
        *(float4*)(xz + (size_t)trow * NCOL + cb) = o0;
        *(float4*)(xz + (size_t)trow * NCOL + cb + 4) = o1;
    }
}

// =========================================================
// Kernel 2: persistent bidirectional LSTM recurrence, v6.
// 16 WGs x 256 thr, fixed roles (wg>>3 = dir, wg&7 = wi).
// Sync: data-as-flag {h, tag} uint2 pairs, device-scope bypass ops.
// hcur2 tags pre-set to 0xFFFFFFFF by memset each launch; each WG
// seeds its own units' {h0, tag=0} before the loop. Consumer at step
// s polls slot s&1 for tag==s (h of step s-1; tag 0 == h0).
// Lap-safety: producer writes slot (s+1)&1 only after its own step-s
// polls passed, which transitively requires every consumer of slot
// s&1 to have finished reading it. Compute identical to round-2 pass.
// =========================================================
__global__ void __launch_bounds__(256, 2) lstm_rec(
    const float* __restrict__ Whh_f, const float* __restrict__ Whh_b,
    const float* __restrict__ h0, const float* __restrict__ c0,
    const float* __restrict__ xz, uint2* __restrict__ hcur2,
    float* __restrict__ lstm_out)
{
    __shared__ float red[4][16][8];
    __shared__ float actb[128];
    const int wg = blockIdx.x;
    const int dir = wg >> 3;        // 0 fwd, 1 bwd
    const int wi = wg & 7;          // index within direction
    const int ub = wi * 32;         // first hidden unit owned
    const int tid = threadIdx.x;
    const int kg = tid >> 4;        // 0..15  k-slice (16 wide)
    const int rg = tid & 15;        // 0..15  row group (8 rows each)
    const int k0 = kg * 16;
    const float* Whh = dir ? Whh_b : Whh_f;

    // load weights into registers: 8 rows x 16 k, pinned via asm touch
    float w[8][16];
#pragma unroll
    for (int q = 0; q < 8; ++q) {
        const int lr = rg * 8 + q;                      // 0..127
        const int grow = (lr >> 5) * 256 + ub + (lr & 31);
        const float* wr = Whh + (size_t)grow * 256 + k0;
#pragma unroll
        for (int kk = 0; kk < 16; kk += 4) {
            float4 v = *(const float4*)(wr + kk);
            w[q][kk] = v.x; w[q][kk + 1] = v.y; w[q][kk + 2] = v.z; w[q][kk + 3] = v.w;
        }
    }
#pragma unroll
    for (int q = 0; q < 8; ++q)
#pragma unroll
        for (int kk = 0; kk < 16; ++kk)
            asm volatile("" : "+v"(w[q][kk]));   // keep register-resident

    // seed cell state and {h0, tag=0} for this WG's own units
    float cst = 0.f;
    if (tid < 32) {
        cst = c0[dir * 256 + ub + tid];
        uint2 iv;
        iv.x = __float_as_uint(h0[dir * 256 + ub + tid]);
        iv.y = 0u;
        st_pair_dev(hcur2 + (size_t)dir * 256 + ub + tid, iv);   // slot 0
    }
    // z-row mapping for tid<128: row = tid -> gate=tid>>5, unit=tid&31
    const int zcol = dir * 1024 + (tid >> 5) * 256 + ub + (tid & 31);

    for (int step = 0; step < S; ++step) {
        // prefetch input part (plain cached load; overlaps the poll)
        float xzv = 0.f;
        if (tid < 128) {
            const int tz = dir ? (S - 1 - step) : step;
            xzv = xz[(size_t)tz * NCOL + zcol];
        }
        // poll the data itself: 16 {h, tag} pairs of this k-slice
        const uint2* hb = hcur2 + ((size_t)(step & 1) * 2 + dir) * 256 + k0;
        float h16[16];
        while (!try_h16(hb, (unsigned)step, h16)) {}

        float acc[8];
#pragma unroll
        for (int q = 0; q < 8; ++q) acc[q] = 0.f;
#pragma unroll
        for (int kk = 0; kk < 16; ++kk)
#pragma unroll
            for (int q = 0; q < 8; ++q) acc[q] += w[q][kk] * h16[kk];
        // butterfly over the 4 k-groups within this wave
#pragma unroll
        for (int q = 0; q < 8; ++q) {
            acc[q] += __shfl_xor(acc[q], 16);
            acc[q] += __shfl_xor(acc[q], 32);
        }
        if ((kg & 3) == 0) {
            const int wv = kg >> 2;
#pragma unroll
            for (int q = 0; q < 8; ++q) red[wv][rg][q] = acc[q];
        }
        __syncthreads();
        if (tid < 128) {
            const int rg2 = tid >> 3, q2 = tid & 7;
            const float z = ((red[0][rg2][q2] + red[1][rg2][q2]) +
                             (red[2][rg2][q2] + red[3][rg2][q2])) + xzv;
            const int gate = tid >> 5;
            actb[tid] = (gate == 2) ? tanhf(z) : (1.f / (1.f + expf(-z)));
        }
        __syncthreads();
        if (tid < 32) {
            const int u = tid;
            const float ig = actb[u];
            const float fg = actb[32 + u];
            const float gg = actb[64 + u];
            const float og = actb[96 + u];
            cst = fg * cst + ig * gg;
            const float h = og * tanhf(cst);
            const int tz = dir ? (S - 1 - step) : step;
            uint2 pv;
            pv.x = __float_as_uint(h);
            pv.y = (unsigned)(step + 1);
            st_pair_dev(hcur2 + ((size_t)((step + 1) & 1) * 2 + dir) * 256 + ub + u, pv);
            lstm_out[(size_t)tz * 512 + dir * 256 + ub + u] = h;   // plain store
        }
    }
}

// =========================================================
// Kernel 3: feats[t][tag] = lstm_out[t] . W_out[tag] + b_out[tag]
// =========================================================
__global__ __launch_bounds__(256) void feats_k(
    const float* __restrict__ lstm, const float* __restrict__ Wout,
    const float* __restrict__ bout, float* __restrict__ feats)
{
    const int gid = blockIdx.x * 256 + threadIdx.x;
    if (gid >= S * NT) return;
    const int t = gid / NT, tag = gid - t * NT;
    const float* hr = lstm + (size_t)t * 512;
    const float* wr = Wout + (size_t)tag * 512;
    float s0 = 0, s1 = 0, s2 = 0, s3 = 0;
#pragma unroll 4
    for (int k = 0; k < 512; k += 4) {
        float4 h4 = *(const float4*)(hr + k);
        float4 w4 = *(const float4*)(wr + k);
        s0 += h4.x * w4.x; s1 += h4.y * w4.y;
        s2 += h4.z * w4.z; s3 += h4.w * w4.w;
    }
    feats[gid] = (s0 + s1) + (s2 + s3) + bout[tag];
}

// tournament combine: strict > keeps earlier index on ties (matches
// jnp.argmax first-occurrence), contiguous pairing preserves order
#define TCOMB(sa, ia, sb, ib, so, io) \
    { const bool g_ = (sb) > (sa); so = g_ ? (sb) : (sa); io = g_ ? (ib) : (ia); }

// =========================================================
// Kernel 4a: Viterbi forward pass. ONE 64-thread wave, own kernel so
// the register allocator has the full budget (no 48-reg persistent
// arrays: trans staged in LDS, read conflict-free; v double-buffered
// in LDS). Exact reference fp order (v[i]+T[i][j])+obs[j], first-index
// tie-break tournament. Writes bps + final argmax.
// =========================================================
__global__ void __launch_bounds__(64, 1) viterbi_fwd(
    const float* __restrict__ feats, const float* __restrict__ trans,
    unsigned char* __restrict__ bps, int* __restrict__ last)
{
    __shared__ float Tsh[NT * NT];
    __shared__ float vb[2][NT];
    const int tid = threadIdx.x;
    for (int i = tid; i < NT * NT; i += 64) Tsh[i] = trans[i];
    if (tid < NT) vb[0][tid] = feats[tid];
    __syncthreads();

    const bool act = tid < NT;
    const int j = act ? tid : 0;
    float obs = feats[NT + j];
    int p = 0;
    for (int t = 1; t < S; ++t) {
        const float obs_n = (t < S - 1) ? feats[(size_t)(t + 1) * NT + j] : 0.f;
        float v[NT];
#pragma unroll
        for (int i = 0; i < NT; i += 4) {
            float4 q = *(const float4*)&vb[p][i];
            v[i] = q.x; v[i + 1] = q.y; v[i + 2] = q.z; v[i + 3] = q.w;
        }
        float sc[NT];
#pragma unroll
        for (int i = 0; i < NT; ++i) sc[i] = (v[i] + Tsh[i * NT + j]) + obs;
        float s24[24]; int i24[24];
#pragma unroll
        for (int q = 0; q < 24; ++q)
            TCOMB(sc[2 * q], 2 * q, sc[2 * q + 1], 2 * q + 1, s24[q], i24[q]);
        float s12[12]; int i12[12];
#pragma unroll
        for (int q = 0; q < 12; ++q)
            TCOMB(s24[2 * q], i24[2 * q], s24[2 * q + 1], i24[2 * q + 1], s12[q], i12[q]);
        float s6[6]; int i6[6];
#pragma unroll
        for (int q = 0; q < 6; ++q)
            TCOMB(s12[2 * q], i12[2 * q], s12[2 * q + 1], i12[2 * q + 1], s6[q], i6[q]);
        float s3[3]; int i3[3];
#pragma unroll
        for (int q = 0; q < 3; ++q)
            TCOMB(s6[2 * q], i6[2 * q], s6[2 * q + 1], i6[2 * q + 1], s3[q], i3[q]);
        float sA; int iA;
        TCOMB(s3[0], i3[0], s3[1], i3[1], sA, iA);
        float sB; int iB;
        TCOMB(sA, iA, s3[2], i3[2], sB, iB);

        if (act) {
            vb[p ^ 1][j] = sB;
            bps[(size_t)(t - 1) * NT + j] = (unsigned char)iB;
        }
        asm volatile("s_waitcnt lgkmcnt(0)" ::: "memory");
        obs = obs_n;
        p ^= 1;
    }
    if (tid == 0) {
        float b = -1e30f; int bi = 0;
        for (int q = 0; q < NT; ++q) { if (vb[p][q] > b) { b = vb[p][q]; bi = q; } }
        last[0] = bi;
    }
}

// =========================================================
// Kernel 4b: chunked parallel backtrack. 256 threads.
// =========================================================
__global__ void __launch_bounds__(256, 1) viterbi_back(
    const unsigned char* __restrict__ bps, const int* __restrict__ last,
    unsigned char* __restrict__ pathA, int* __restrict__ out)
{
    __shared__ unsigned char cmap[64][NT];
    __shared__ int SB[65];
    const int tid = threadIdx.x;

    // Phase A: 64 chunks x 48 states, 12 tasks/thread, ILP-12 chains
    int cArr[12], sArr[12];
    unsigned char stv[12];
#pragma unroll
    for (int r = 0; r < 12; ++r) {
        const int task = r * 256 + tid;
        cArr[r] = task / NT;
        sArr[r] = task - cArr[r] * NT;
        stv[r] = (unsigned char)sArr[r];
    }
    for (int stp = 31; stp >= 0; --stp) {
#pragma unroll
        for (int r = 0; r < 12; ++r) {
            const int km = cArr[r] * 32 + stp;
            if (km < S - 1) stv[r] = bps[(size_t)km * NT + stv[r]];
            pathA[(size_t)(cArr[r] * NT + sArr[r]) * 32 + stp] = stv[r];
        }
    }
#pragma unroll
    for (int r = 0; r < 12; ++r) cmap[cArr[r]][sArr[r]] = stv[r];
    __syncthreads();
    // Phase B: sequential chunk-boundary states
    if (tid == 0) {
        SB[64] = last[0];
        for (int c = 63; c >= 0; --c) SB[c] = cmap[c][SB[c + 1]];
    }
    __syncthreads();
    // Phase C: emit path
    for (int t = tid; t < S; t += 256) {
        const int c = t >> 5;
        out[t] = (int)pathA[(size_t)(c * NT + SB[c + 1]) * 32 + (t & 31)];
    }
}

// =========================================================
extern "C" void kernel_launch(void* const* d_in, const int* in_sizes, int n_in,
                              void* d_out, int out_size, void* d_ws, size_t ws_size,
                              hipStream_t stream) {
    const int*   sent   = (const int*)d_in[0];
    const float* emb    = (const float*)d_in[1];
    const float* Wih_f  = (const float*)d_in[2];
    const float* Whh_f  = (const float*)d_in[3];
    const float* b_f    = (const float*)d_in[4];
    const float* Wih_b  = (const float*)d_in[5];
    const float* Whh_b  = (const float*)d_in[6];
    const float* b_b    = (const float*)d_in[7];
    const float* W_out  = (const float*)d_in[8];
    const float* b_out  = (const float*)d_in[9];
    const float* trans  = (const float*)d_in[10];
    const float* h0     = (const float*)d_in[11];
    const float* c0     = (const float*)d_in[12];
    int* out = (int*)d_out;

    char* ws = (char*)d_ws;
    float* xz       = (float*)(ws + XZ_OFF);
    float* lstm     = (float*)(ws + LSTM_OFF);
    float* feats    = (float*)(ws + FEATS_OFF);
    uint2* hcur2    = (uint2*)(ws + HCUR2_OFF);
    int*   last     = (int*)(ws + LAST_OFF);
    unsigned char* bps   = (unsigned char*)(ws + BPS_OFF);
    unsigned char* pathA = (unsigned char*)(ws + PATHA_OFF);

    // reset tags so no stale {h, tag} pair from a previous replay can
    // alias a wanted tag (tags are exact-match, 0..2048)
    hipMemsetAsync(hcur2, 0xFF, HCUR2_BYTES, stream);

    gemm_xz<<<dim3(16, 16), 256, 0, stream>>>(sent, emb, Wih_f, Wih_b, b_f, b_b, xz);

    lstm_rec<<<dim3(NWG), 256, 0, stream>>>(Whh_f, Whh_b, h0, c0, xz, hcur2, lstm);

    feats_k<<<dim3((S * NT + 255) / 256), 256, 0, stream>>>(lstm, W_out, b_out, feats);

    viterbi_fwd<<<dim3(1), 64, 0, stream>>>(feats, trans, bps, last);
    viterbi_back<<<dim3(1), 256, 0, stream>>>(bps, last, pathA, out);
}

// Round 7
// 5654.358 us; speedup vs baseline: 9.6705x; 2.7701x over previous
//
#include <hip/hip_runtime.h>
#include <hip/hip_bf16.h>
#include <math.h>

// Problem constants
#define S   2048
#define E   256
#define HD  256
#define NCOL 2048   // 2 dirs * 4 gates * HD
#define NT  48
#define NWG 16      // recurrence workgroups (8 per direction)

// ---------------- workspace layout (bytes) ----------------
#define XZ_OFF      ((size_t)0)                         // float[S][2048]
#define XZ_BYTES    ((size_t)S * 2048 * 4)
#define LSTM_OFF    (XZ_OFF + XZ_BYTES)                 // float[S][512]
#define LSTM_BYTES  ((size_t)S * 512 * 4)
#define FEATS_OFF   (LSTM_OFF + LSTM_BYTES)             // float[S][48]
#define FEATS_BYTES ((size_t)S * NT * 4)
#define HCUR2_OFF   (FEATS_OFF + FEATS_BYTES)           // uint2[2 slot][2 dir][256]
#define HCUR2_BYTES ((size_t)2 * 2 * 256 * 8)
#define BPS_OFF     (HCUR2_OFF + HCUR2_BYTES)           // u8[2048][48]
#define BPS_BYTES   ((size_t)S * NT)
#define PATHA_OFF   (BPS_OFF + BPS_BYTES)               // u8[3072][32]
#define PATHA_BYTES ((size_t)3072 * 32)

// =========================================================
// Device-scope bypass ops. Data-as-flag: h stored as {f32 bits, step tag}
// uint2 per unit (single 8B store -> value+tag land atomically).
// Consumer polls the 16 pairs it needs (8 x dwordx4 sc0 sc1) and checks
// all 16 tags; success delivers the h data in the same loads.
// =========================================================
__device__ __forceinline__ void st_pair_dev(uint2* p, uint2 v) {
    asm volatile("global_store_dwordx2 %0, %1, off sc0 sc1"
                 :: "v"(p), "v"(v) : "memory");
}

__device__ __forceinline__ bool try_h16(const uint2* p, unsigned want,
                                        float h16[16]) {
    uint4 a, b, c, d, e, f, g, h;
    asm volatile(
        "global_load_dwordx4 %0, %8, off sc0 sc1\n\t"
        "global_load_dwordx4 %1, %8, off offset:16 sc0 sc1\n\t"
        "global_load_dwordx4 %2, %8, off offset:32 sc0 sc1\n\t"
        "global_load_dwordx4 %3, %8, off offset:48 sc0 sc1\n\t"
        "global_load_dwordx4 %4, %8, off offset:64 sc0 sc1\n\t"
        "global_load_dwordx4 %5, %8, off offset:80 sc0 sc1\n\t"
        "global_load_dwordx4 %6, %8, off offset:96 sc0 sc1\n\t"
        "global_load_dwordx4 %7, %8, off offset:112 sc0 sc1\n\t"
        "s_waitcnt vmcnt(0)"
        : "=&v"(a), "=&v"(b), "=&v"(c), "=&v"(d),
          "=&v"(e), "=&v"(f), "=&v"(g), "=&v"(h)
        : "v"(p)
        : "memory");
    const unsigned bad =
        (a.y ^ want) | (a.w ^ want) | (b.y ^ want) | (b.w ^ want) |
        (c.y ^ want) | (c.w ^ want) | (d.y ^ want) | (d.w ^ want) |
        (e.y ^ want) | (e.w ^ want) | (f.y ^ want) | (f.w ^ want) |
        (g.y ^ want) | (g.w ^ want) | (h.y ^ want) | (h.w ^ want);
    if (bad) return false;
    h16[0]  = __uint_as_float(a.x); h16[1]  = __uint_as_float(a.z);
    h16[2]  = __uint_as_float(b.x); h16[3]  = __uint_as_float(b.z);
    h16[4]  = __uint_as_float(c.x); h16[5]  = __uint_as_float(c.z);
    h16[6]  = __uint_as_float(d.x); h16[7]  = __uint_as_float(d.z);
    h16[8]  = __uint_as_float(e.x); h16[9]  = __uint_as_float(e.z);
    h16[10] = __uint_as_float(f.x); h16[11] = __uint_as_float(f.z);
    h16[12] = __uint_as_float(g.x); h16[13] = __uint_as_float(g.z);
    h16[14] = __uint_as_float(h.x); h16[15] = __uint_as_float(h.z);
    return true;
}

// =========================================================
// Kernel 1: xz[t][col] = emb[sent[t]] @ [Wih_f;Wih_b].T + [b_f;b_b]
// =========================================================
__global__ __launch_bounds__(256) void gemm_xz(
    const int* __restrict__ sent, const float* __restrict__ emb,
    const float* __restrict__ Wih_f, const float* __restrict__ Wih_b,
    const float* __restrict__ b_f, const float* __restrict__ b_b,
    float* __restrict__ xz)
{
    __shared__ float As[16][132];
    __shared__ float Bs[16][132];
    const int tid = threadIdx.x;
    const int bm = blockIdx.x * 128;   // t tile
    const int bn = blockIdx.y * 128;   // col tile
    const int tx = tid & 15, ty = tid >> 4;
    const int lm = tid >> 1, kq = (tid & 1) * 8;

    const int srow = sent[bm + lm];
    const float* arow = emb + (size_t)srow * E;
    const int bcol = bn + lm;
    const float* brow = (bcol < 1024) ? (Wih_f + (size_t)bcol * E)
                                      : (Wih_b + (size_t)(bcol - 1024) * E);
    float acc[8][8];
#pragma unroll
    for (int i = 0; i < 8; ++i)
#pragma unroll
        for (int j = 0; j < 8; ++j) acc[i][j] = 0.f;

    for (int k0 = 0; k0 < 256; k0 += 16) {
        float4 a0 = *(const float4*)(arow + k0 + kq);
        float4 a1 = *(const float4*)(arow + k0 + kq + 4);
        float4 c0v = *(const float4*)(brow + k0 + kq);
        float4 c1v = *(const float4*)(brow + k0 + kq + 4);
        __syncthreads();
        As[kq + 0][lm] = a0.x; As[kq + 1][lm] = a0.y; As[kq + 2][lm] = a0.z; As[kq + 3][lm] = a0.w;
        As[kq + 4][lm] = a1.x; As[kq + 5][lm] = a1.y; As[kq + 6][lm] = a1.z; As[kq + 7][lm] = a1.w;
        Bs[kq + 0][lm] = c0v.x; Bs[kq + 1][lm] = c0v.y; Bs[kq + 2][lm] = c0v.z; Bs[kq + 3][lm] = c0v.w;
        Bs[kq + 4][lm] = c1v.x; Bs[kq + 5][lm] = c1v.y; Bs[kq + 6][lm] = c1v.z; Bs[kq + 7][lm] = c1v.w;
        __syncthreads();
#pragma unroll
        for (int k = 0; k < 16; ++k) {
            float av[8], bv[8];
            *(float4*)&av[0] = *(const float4*)&As[k][ty * 8];
            *(float4*)&av[4] = *(const float4*)&As[k][ty * 8 + 4];
            *(float4*)&bv[0] = *(const float4*)&Bs[k][tx * 8];
            *(float4*)&bv[4] = *(const float4*)&Bs[k][tx * 8 + 4];
#pragma unroll
            for (int i = 0; i < 8; ++i)
#pragma unroll
                for (int j = 0; j < 8; ++j) acc[i][j] += av[i] * bv[j];
        }
    }
    float bias[8];
    const int cb = bn + tx * 8;
    const float* bptr = (cb < 1024) ? (b_f + cb) : (b_b + cb - 1024);
    *(float4*)&bias[0] = *(const float4*)bptr;
    *(float4*)&bias[4] = *(const float4*)(bptr + 4);
#pragma unroll
    for (int i = 0; i < 8; ++i) {
        const int trow = bm + ty * 8 + i;
        float4 o0, o1;
        o0.x = acc[i][0] + bias[0]; o0.y = acc[i][1] + bias[1];
        o0.z = acc[i][2] + bias[2]; o0.w = acc[i][3] + bias[3];
        o1.x = acc[i][4] + bias[4]; o1.y = acc[i][5] + bias[5];
        o1.z = acc[i][6] + bias[6]; o1.w = acc[i][7] + bias[7];
        *(float4*)(xz + (size_t)trow * NCOL + cb) = o0;
        *(float4*)(xz + (size_t)trow * NCOL + cb + 4) = o1;
    }
}

// =========================================================
// Kernel 2: persistent bidirectional LSTM recurrence, v6 (unchanged
// from round 6 — it improved to ~3.75 ms). 16 WGs x 256 thr, fixed
// roles. Sync: data-as-flag {h, tag} uint2 pairs, device-scope ops.
// =========================================================
__global__ void __launch_bounds__(256, 2) lstm_rec(
    const float* __restrict__ Whh_f, const float* __restrict__ Whh_b,
    const float* __restrict__ h0, const float* __restrict__ c0,
    const float* __restrict__ xz, uint2* __restrict__ hcur2,
    float* __restrict__ lstm_out)
{
    __shared__ float red[4][16][8];
    __shared__ float actb[128];
    const int wg = blockIdx.x;
    const int dir = wg >> 3;        // 0 fwd, 1 bwd
    const int wi = wg & 7;          // index within direction
    const int ub = wi * 32;         // first hidden unit owned
    const int tid = threadIdx.x;
    const int kg = tid >> 4;        // 0..15  k-slice (16 wide)
    const int rg = tid & 15;        // 0..15  row group (8 rows each)
    const int k0 = kg * 16;
    const float* Whh = dir ? Whh_b : Whh_f;

    // load weights into registers: 8 rows x 16 k, pinned via asm touch
    float w[8][16];
#pragma unroll
    for (int q = 0; q < 8; ++q) {
        const int lr = rg * 8 + q;                      // 0..127
        const int grow = (lr >> 5) * 256 + ub + (lr & 31);
        const float* wr = Whh + (size_t)grow * 256 + k0;
#pragma unroll
        for (int kk = 0; kk < 16; kk += 4) {
            float4 v = *(const float4*)(wr + kk);
            w[q][kk] = v.x; w[q][kk + 1] = v.y; w[q][kk + 2] = v.z; w[q][kk + 3] = v.w;
        }
    }
#pragma unroll
    for (int q = 0; q < 8; ++q)
#pragma unroll
        for (int kk = 0; kk < 16; ++kk)
            asm volatile("" : "+v"(w[q][kk]));   // keep register-resident

    // seed cell state and {h0, tag=0} for this WG's own units
    float cst = 0.f;
    if (tid < 32) {
        cst = c0[dir * 256 + ub + tid];
        uint2 iv;
        iv.x = __float_as_uint(h0[dir * 256 + ub + tid]);
        iv.y = 0u;
        st_pair_dev(hcur2 + (size_t)dir * 256 + ub + tid, iv);   // slot 0
    }
    // z-row mapping for tid<128: row = tid -> gate=tid>>5, unit=tid&31
    const int zcol = dir * 1024 + (tid >> 5) * 256 + ub + (tid & 31);

    for (int step = 0; step < S; ++step) {
        // prefetch input part (plain cached load; overlaps the poll)
        float xzv = 0.f;
        if (tid < 128) {
            const int tz = dir ? (S - 1 - step) : step;
            xzv = xz[(size_t)tz * NCOL + zcol];
        }
        // poll the data itself: 16 {h, tag} pairs of this k-slice
        const uint2* hb = hcur2 + ((size_t)(step & 1) * 2 + dir) * 256 + k0;
        float h16[16];
        while (!try_h16(hb, (unsigned)step, h16)) {}

        float acc[8];
#pragma unroll
        for (int q = 0; q < 8; ++q) acc[q] = 0.f;
#pragma unroll
        for (int kk = 0; kk < 16; ++kk)
#pragma unroll
            for (int q = 0; q < 8; ++q) acc[q] += w[q][kk] * h16[kk];
        // butterfly over the 4 k-groups within this wave
#pragma unroll
        for (int q = 0; q < 8; ++q) {
            acc[q] += __shfl_xor(acc[q], 16);
            acc[q] += __shfl_xor(acc[q], 32);
        }
        if ((kg & 3) == 0) {
            const int wv = kg >> 2;
#pragma unroll
            for (int q = 0; q < 8; ++q) red[wv][rg][q] = acc[q];
        }
        __syncthreads();
        if (tid < 128) {
            const int rg2 = tid >> 3, q2 = tid & 7;
            const float z = ((red[0][rg2][q2] + red[1][rg2][q2]) +
                             (red[2][rg2][q2] + red[3][rg2][q2])) + xzv;
            const int gate = tid >> 5;
            actb[tid] = (gate == 2) ? tanhf(z) : (1.f / (1.f + expf(-z)));
        }
        __syncthreads();
        if (tid < 32) {
            const int u = tid;
            const float ig = actb[u];
            const float fg = actb[32 + u];
            const float gg = actb[64 + u];
            const float og = actb[96 + u];
            cst = fg * cst + ig * gg;
            const float h = og * tanhf(cst);
            const int tz = dir ? (S - 1 - step) : step;
            uint2 pv;
            pv.x = __float_as_uint(h);
            pv.y = (unsigned)(step + 1);
            st_pair_dev(hcur2 + ((size_t)((step + 1) & 1) * 2 + dir) * 256 + ub + u, pv);
            lstm_out[(size_t)tz * 512 + dir * 256 + ub + u] = h;   // plain store
        }
    }
}

// =========================================================
// Kernel 3: feats[t][tag] = lstm_out[t] . W_out[tag] + b_out[tag]
// =========================================================
__global__ __launch_bounds__(256) void feats_k(
    const float* __restrict__ lstm, const float* __restrict__ Wout,
    const float* __restrict__ bout, float* __restrict__ feats)
{
    const int gid = blockIdx.x * 256 + threadIdx.x;
    if (gid >= S * NT) return;
    const int t = gid / NT, tag = gid - t * NT;
    const float* hr = lstm + (size_t)t * 512;
    const float* wr = Wout + (size_t)tag * 512;
    float s0 = 0, s1 = 0, s2 = 0, s3 = 0;
#pragma unroll 4
    for (int k = 0; k < 512; k += 4) {
        float4 h4 = *(const float4*)(hr + k);
        float4 w4 = *(const float4*)(wr + k);
        s0 += h4.x * w4.x; s1 += h4.y * w4.y;
        s2 += h4.z * w4.z; s3 += h4.w * w4.w;
    }
    feats[gid] = (s0 + s1) + (s2 + s3) + bout[tag];
}

// =========================================================
// Kernel 4: Viterbi — round-2 PROVEN structure restored verbatim.
// Forward: 192 active threads (48 tags x 4 i-groups), Treg[12]/thread
// (small, no spill), LDS v2 double buffer, one __syncthreads per step,
// exact reference fp order (v[i]+T[i,j])+obs[j], first-index tie-break
// via shfl_xor reduce. Then chunked parallel backtrack.
// =========================================================
__global__ void __launch_bounds__(256, 1) viterbi_k(
    const float* __restrict__ feats, const float* __restrict__ trans,
    unsigned char* __restrict__ bps, unsigned char* __restrict__ pathA,
    int* __restrict__ out)
{
    __shared__ float v2[2][NT];
    __shared__ unsigned char cmap[64][NT];
    __shared__ int SB[65];
    __shared__ int last_s;
    const int tid = threadIdx.x;
    const int j = tid >> 2, ig = tid & 3;
    const bool act = (tid < 192);

    float Treg[12];
    if (act) {
#pragma unroll
        for (int r = 0; r < 12; ++r) Treg[r] = trans[(ig * 12 + r) * NT + j];
    }
    if (tid < NT) v2[0][tid] = feats[tid];
    __syncthreads();

    float obs_c = 0.f;
    if (act) obs_c = feats[NT + j];
    for (int t = 1; t < S; ++t) {
        float obs_n = 0.f;
        if (act && t < S - 1) obs_n = feats[(size_t)(t + 1) * NT + j];
        const int p = (t - 1) & 1;
        if (act) {
            float best = -1e30f; int bi = 0;
#pragma unroll
            for (int r = 0; r < 12; ++r) {
                const int i = ig * 12 + r;
                const float sc = (v2[p][i] + Treg[r]) + obs_c;
                if (sc > best) { best = sc; bi = i; }
            }
            // reduce across the 4 i-groups; first-index wins ties
            {
                float ob = __shfl_xor(best, 1); int obi = __shfl_xor(bi, 1);
                if (ob > best || (ob == best && obi < bi)) { best = ob; bi = obi; }
                ob = __shfl_xor(best, 2); obi = __shfl_xor(bi, 2);
                if (ob > best || (ob == best && obi < bi)) { best = ob; bi = obi; }
            }
            if (ig == 0) {
                v2[p ^ 1][j] = best;
                bps[(size_t)(t - 1) * NT + j] = (unsigned char)bi;
            }
        }
        __syncthreads();
        obs_c = obs_n;
    }
    // last = argmax of final v (stored in v2[1]); first occurrence
    if (tid == 0) {
        float b = -1e30f; int bi = 0;
        for (int q = 0; q < NT; ++q) { if (v2[1][q] > b) { b = v2[1][q]; bi = q; } }
        last_s = bi;
    }
    // Phase A: 64 chunks x 48 states, 12 tasks/thread, ILP-12 chains
    int cArr[12], sArr[12];
    unsigned char stv[12];
#pragma unroll
    for (int r = 0; r < 12; ++r) {
        const int task = r * 256 + tid;
        cArr[r] = task / NT;
        sArr[r] = task - cArr[r] * NT;
        stv[r] = (unsigned char)sArr[r];
    }
    for (int stp = 31; stp >= 0; --stp) {
#pragma unroll
        for (int r = 0; r < 12; ++r) {
            const int km = cArr[r] * 32 + stp;
            if (km < S - 1) stv[r] = bps[(size_t)km * NT + stv[r]];
            pathA[(size_t)(cArr[r] * NT + sArr[r]) * 32 + stp] = stv[r];
        }
    }
#pragma unroll
    for (int r = 0; r < 12; ++r) cmap[cArr[r]][sArr[r]] = stv[r];
    __syncthreads();
    // Phase B: sequential chunk-boundary states
    if (tid == 0) {
        SB[64] = last_s;
        for (int c = 63; c >= 0; --c) SB[c] = cmap[c][SB[c + 1]];
    }
    __syncthreads();
    // Phase C: emit path
    for (int t = tid; t < S; t += 256) {
        const int c = t >> 5;
        out[t] = (int)pathA[(size_t)(c * NT + SB[c + 1]) * 32 + (t & 31)];
    }
}

// =========================================================
extern "C" void kernel_launch(void* const* d_in, const int* in_sizes, int n_in,
                              void* d_out, int out_size, void* d_ws, size_t ws_size,
                              hipStream_t stream) {
    const int*   sent   = (const int*)d_in[0];
    const float* emb    = (const float*)d_in[1];
    const float* Wih_f  = (const float*)d_in[2];
    const float* Whh_f  = (const float*)d_in[3];
    const float* b_f    = (const float*)d_in[4];
    const float* Wih_b  = (const float*)d_in[5];
    const float* Whh_b  = (const float*)d_in[6];
    const float* b_b    = (const float*)d_in[7];
    const float* W_out  = (const float*)d_in[8];
    const float* b_out  = (const float*)d_in[9];
    const float* trans  = (const float*)d_in[10];
    const float* h0     = (const float*)d_in[11];
    const float* c0     = (const float*)d_in[12];
    int* out = (int*)d_out;

    char* ws = (char*)d_ws;
    float* xz       = (float*)(ws + XZ_OFF);
    float* lstm     = (float*)(ws + LSTM_OFF);
    float* feats    = (float*)(ws + FEATS_OFF);
    uint2* hcur2    = (uint2*)(ws + HCUR2_OFF);
    unsigned char* bps   = (unsigned char*)(ws + BPS_OFF);
    unsigned char* pathA = (unsigned char*)(ws + PATHA_OFF);

    // reset tags so no stale {h, tag} pair from a previous replay can
    // alias a wanted tag (tags are exact-match, 0..2048)
    hipMemsetAsync(hcur2, 0xFF, HCUR2_BYTES, stream);

    gemm_xz<<<dim3(16, 16), 256, 0, stream>>>(sent, emb, Wih_f, Wih_b, b_f, b_b, xz);

    lstm_rec<<<dim3(NWG), 256, 0, stream>>>(Whh_f, Whh_b, h0, c0, xz, hcur2, lstm);

    feats_k<<<dim3((S * NT + 255) / 256), 256, 0, stream>>>(lstm, W_out, b_out, feats);

    viterbi_k<<<dim3(1), 256, 0, stream>>>(feats, trans, bps, pathA, out);
}